// Round 1
// baseline (780.379 us; speedup 1.0000x reference)
//
#include <hip/hip_runtime.h>

// ---------------------------------------------------------------------------
// Actor: GRU over V=20 vehicle slots (H=256) + MLP head 271->1024->1024->512->256->1
// B=16384, F=15. All GEMMs in bf16 MFMA (16x16x32), fp32 accumulate.
// ---------------------------------------------------------------------------

typedef __attribute__((ext_vector_type(8))) __bf16 bf16x8;
typedef __attribute__((ext_vector_type(4))) float  floatx4;

#define MFMA16(a, b, c) __builtin_amdgcn_mfma_f32_16x16x32_bf16((a), (b), (c), 0, 0, 0)

__device__ __forceinline__ float sigmoid_f(float x) { return 1.f / (1.f + __expf(-x)); }
__device__ __forceinline__ float tanh_f(float x)    { return 1.f - 2.f / (1.f + __expf(2.f * x)); }

// ---------------------------------------------------------------------------
// Weight prep: pack everything to bf16 in workspace.
//   Wg1  [512][288]  rows g in {r(0..255), z(256..511)}: [W_ih[g][0..14] | 0 x17 | W_hh[g][0..255]]
//   W1p  [1024][288] : [W1[o][0..14] | 0 x17 | W1[o][15..270]]
//   W2b  [1024][1024], W3b [512][1024], W4b [256][512]  : direct cvt
//   Win_n[256][32]   : [W_ih[512+j][0..14] | 0]
//   Whh_n[256][256]  : W_hh rows 512..767
//   bsum [512] = b_ih+b_hh (r,z);  bihn[256]=b_ih[512+]; bhhn[256]=b_hh[512+]
// ---------------------------------------------------------------------------
#define S0 147456u    // Wg1
#define S1 442368u    // + W1p (294912)
#define S2 1490944u   // + W2b (1048576)
#define S3 2015232u   // + W3b (524288)
#define S4 2146304u   // + W4b (131072)
#define S5 2154496u   // + Win_n (8192)
#define S6 2220032u   // + Whh_n (65536)
#define S7 2220544u   // + bsum (512)
#define S8 2221056u   // + bihn/bhhn (512)

__global__ void prep_kernel(const float* __restrict__ W_ih, const float* __restrict__ W_hh,
                            const float* __restrict__ b_ih, const float* __restrict__ b_hh,
                            const float* __restrict__ W1, const float* __restrict__ W2,
                            const float* __restrict__ W3, const float* __restrict__ W4,
                            __bf16* __restrict__ Wg1, __bf16* __restrict__ W1p,
                            __bf16* __restrict__ W2b, __bf16* __restrict__ W3b,
                            __bf16* __restrict__ W4b, __bf16* __restrict__ Win_n,
                            __bf16* __restrict__ Whh_n, float* __restrict__ bsum,
                            float* __restrict__ bihn, float* __restrict__ bhhn)
{
    for (unsigned i = blockIdx.x * blockDim.x + threadIdx.x; i < S8; i += gridDim.x * blockDim.x) {
        if (i < S0) {
            unsigned g = i / 288u, c = i % 288u;
            float v = (c < 15u) ? W_ih[g * 15u + c] : ((c < 32u) ? 0.f : W_hh[g * 256u + (c - 32u)]);
            Wg1[i] = (__bf16)v;
        } else if (i < S1) {
            unsigned t = i - S0, o = t / 288u, c = t % 288u;
            float v = (c < 15u) ? W1[o * 271u + c] : ((c < 32u) ? 0.f : W1[o * 271u + (c - 17u)]);
            W1p[t] = (__bf16)v;
        } else if (i < S2) {
            unsigned t = i - S1; W2b[t] = (__bf16)W2[t];
        } else if (i < S3) {
            unsigned t = i - S2; W3b[t] = (__bf16)W3[t];
        } else if (i < S4) {
            unsigned t = i - S3; W4b[t] = (__bf16)W4[t];
        } else if (i < S5) {
            unsigned t = i - S4, j = t / 32u, c = t % 32u;
            Win_n[t] = (__bf16)((c < 15u) ? W_ih[(512u + j) * 15u + c] : 0.f);
        } else if (i < S6) {
            unsigned t = i - S5; Whh_n[t] = (__bf16)W_hh[512u * 256u + t];
        } else if (i < S7) {
            unsigned t = i - S6; bsum[t] = b_ih[t] + b_hh[t];
        } else {
            unsigned t = i - S7;
            if (t < 256u) bihn[t] = b_ih[512u + t];
            else          bhhn[t - 256u] = b_hh[512u + t - 256u];
        }
    }
}

// ---------------------------------------------------------------------------
// GRU kernel. 256 blocks x 512 threads (8 waves). 64 batch rows per block.
// h double-buffered in LDS (bf16, XOR-swizzled 16B chunks); fp32 h copy kept in
// registers (D-layout) for the z*h term. Wave w owns gate columns w*32..w*32+31
// so r/z/xn/hn accumulators align elementwise.  One barrier per step.
// ---------------------------------------------------------------------------
__global__ __launch_bounds__(512, 2)
void gru_kernel(const float* __restrict__ state,
                const __bf16* __restrict__ Wg1,  const __bf16* __restrict__ Win_n,
                const __bf16* __restrict__ Whh_n,
                const float* __restrict__ bsum, const float* __restrict__ bihn,
                const float* __restrict__ bhhn, __bf16* __restrict__ x0)
{
    __shared__ __bf16 hbuf[2][64 * 256];   // 64 KiB total, 2 buffers
    const int tid  = threadIdx.x;
    const int wave = tid >> 6;
    const int lane = tid & 63;
    const int quad = lane >> 4;
    const int ln   = lane & 15;
    const int b0   = blockIdx.x * 64;

    {   // zero h buffer 0 (h0 = 0)
        bf16x8 z = {};
        bf16x8* p = (bf16x8*)&hbuf[0][0];
        for (int i = tid; i < 64 * 256 / 8; i += 512) p[i] = z;
    }

    const int j0 = wave * 32 + ln;
    const int j1 = j0 + 16;
    const float bsr0 = bsum[j0],       bsr1 = bsum[j1];
    const float bsz0 = bsum[256 + j0], bsz1 = bsum[256 + j1];
    const float bin0 = bihn[j0],       bin1 = bihn[j1];
    const float bhn0 = bhhn[j0],       bhn1 = bhhn[j1];

    float hreg[4][2][4];
    #pragma unroll
    for (int m = 0; m < 4; m++)
        #pragma unroll
        for (int jt = 0; jt < 2; jt++)
            #pragma unroll
            for (int r = 0; r < 4; r++) hreg[m][jt][r] = 0.f;

    const __bf16* wg_r0 = Wg1 + (size_t)j0 * 288;
    const __bf16* wg_r1 = Wg1 + (size_t)j1 * 288;
    const __bf16* wg_z0 = Wg1 + (size_t)(256 + j0) * 288;
    const __bf16* wg_z1 = Wg1 + (size_t)(256 + j1) * 288;
    const __bf16* wn_x0 = Win_n + (size_t)j0 * 32;
    const __bf16* wn_x1 = Win_n + (size_t)j1 * 32;
    const __bf16* wn_h0 = Whh_n + (size_t)j0 * 256;
    const __bf16* wn_h1 = Whh_n + (size_t)j1 * 256;

    __syncthreads();

    #pragma unroll 1
    for (int v = 0; v < 20; ++v) {
        const int rb = v & 1, wb = rb ^ 1;
        floatx4 arz[4][4], axn[4][2], ahn[4][2];
        const floatx4 zf = {0.f, 0.f, 0.f, 0.f};
        #pragma unroll
        for (int m = 0; m < 4; m++) {
            #pragma unroll
            for (int n = 0; n < 4; n++) arz[m][n] = zf;
            axn[m][0] = zf; axn[m][1] = zf; ahn[m][0] = zf; ahn[m][1] = zf;
        }

        // ---- k-tile 0: state features (k=0..31, valid 0..14) ----
        {
            bf16x8 af[4];
            #pragma unroll
            for (int m = 0; m < 4; m++) {
                bf16x8 a = {};
                if (quad < 2) {
                    const float* sp = state + (size_t)(b0 + m * 16 + ln) * 300 + v * 15 + quad * 8;
                    #pragma unroll
                    for (int jj = 0; jj < 8; jj++) {
                        int k = quad * 8 + jj;
                        a[jj] = (k < 15) ? (__bf16)sp[jj] : (__bf16)0.f;
                    }
                }
                af[m] = a;
            }
            const int q8 = quad * 8;
            bf16x8 br0 = *(const bf16x8*)(wg_r0 + q8);
            bf16x8 br1 = *(const bf16x8*)(wg_r1 + q8);
            bf16x8 bz0 = *(const bf16x8*)(wg_z0 + q8);
            bf16x8 bz1 = *(const bf16x8*)(wg_z1 + q8);
            bf16x8 bx0 = *(const bf16x8*)(wn_x0 + q8);
            bf16x8 bx1 = *(const bf16x8*)(wn_x1 + q8);
            #pragma unroll
            for (int m = 0; m < 4; m++) {
                arz[m][0] = MFMA16(af[m], br0, arz[m][0]);
                arz[m][1] = MFMA16(af[m], br1, arz[m][1]);
                arz[m][2] = MFMA16(af[m], bz0, arz[m][2]);
                arz[m][3] = MFMA16(af[m], bz1, arz[m][3]);
                axn[m][0] = MFMA16(af[m], bx0, axn[m][0]);
                axn[m][1] = MFMA16(af[m], bx1, axn[m][1]);
            }
        }

        // ---- k-tiles over h (k = 32..287) ----
        #pragma unroll 2
        for (int kk = 0; kk < 8; ++kk) {
            bf16x8 af[4];
            #pragma unroll
            for (int m = 0; m < 4; m++) {
                int row = m * 16 + ln;
                int ch  = (kk * 4 + quad) ^ (row & 7);   // XOR swizzle, 16B chunks
                af[m] = *((const bf16x8*)&hbuf[rb][0] + row * 32 + ch);
            }
            const int koff = 32 + kk * 32 + quad * 8;
            const int hoff = kk * 32 + quad * 8;
            bf16x8 br0 = *(const bf16x8*)(wg_r0 + koff);
            bf16x8 br1 = *(const bf16x8*)(wg_r1 + koff);
            bf16x8 bz0 = *(const bf16x8*)(wg_z0 + koff);
            bf16x8 bz1 = *(const bf16x8*)(wg_z1 + koff);
            bf16x8 bh0 = *(const bf16x8*)(wn_h0 + hoff);
            bf16x8 bh1 = *(const bf16x8*)(wn_h1 + hoff);
            #pragma unroll
            for (int m = 0; m < 4; m++) {
                arz[m][0] = MFMA16(af[m], br0, arz[m][0]);
                arz[m][1] = MFMA16(af[m], br1, arz[m][1]);
                arz[m][2] = MFMA16(af[m], bz0, arz[m][2]);
                arz[m][3] = MFMA16(af[m], bz1, arz[m][3]);
                ahn[m][0] = MFMA16(af[m], bh0, ahn[m][0]);
                ahn[m][1] = MFMA16(af[m], bh1, ahn[m][1]);
            }
        }

        // ---- gates (all in registers, D-layout) ----
        #pragma unroll
        for (int m = 0; m < 4; m++) {
            #pragma unroll
            for (int jt = 0; jt < 2; jt++) {
                const float bsr = jt ? bsr1 : bsr0;
                const float bsz = jt ? bsz1 : bsz0;
                const float bin = jt ? bin1 : bin0;
                const float bhn = jt ? bhn1 : bhn0;
                const int j = wave * 32 + jt * 16 + ln;
                #pragma unroll
                for (int r = 0; r < 4; r++) {
                    float rg = sigmoid_f(arz[m][jt][r] + bsr);
                    float zg = sigmoid_f(arz[m][2 + jt][r] + bsz);
                    float nn = tanh_f(axn[m][jt][r] + bin + rg * (ahn[m][jt][r] + bhn));
                    float hnew = (1.f - zg) * nn + zg * hreg[m][jt][r];
                    hreg[m][jt][r] = hnew;
                    int row = m * 16 + quad * 4 + r;
                    hbuf[wb][(row * 32 + ((j >> 3) ^ (row & 7))) * 8 + (j & 7)] = (__bf16)hnew;
                }
            }
        }
        __syncthreads();
    }

    // ---- epilogue: x0 = [state[:,0,:] (15) | 0-pad to 32 | h (256)] ----
    #pragma unroll
    for (int m = 0; m < 4; m++)
        #pragma unroll
        for (int jt = 0; jt < 2; jt++)
            #pragma unroll
            for (int r = 0; r < 4; r++) {
                int row = m * 16 + quad * 4 + r;
                int j = wave * 32 + jt * 16 + ln;
                x0[(size_t)(b0 + row) * 288 + 32 + j] = (__bf16)hreg[m][jt][r];
            }
    for (int i = tid; i < 64 * 32; i += 512) {
        int row = i >> 5, c = i & 31;
        float s = (c < 15) ? state[(size_t)(b0 + row) * 300 + c] : 0.f;
        x0[(size_t)(b0 + row) * 288 + c] = (__bf16)s;
    }
}

// ---------------------------------------------------------------------------
// Generic MFMA GEMM:  C[M][N] = act(A[M][K] @ W[N][K]^T + bias), bf16 in/out.
// Block = 256 thr (4 waves, 2x2), block tile 128x128, wave tile 64x64.
// K multiple of 32. Direct global fragment loads (L1/L2 cached).
// ---------------------------------------------------------------------------
__global__ __launch_bounds__(256)
void gemm_bias_act(const __bf16* __restrict__ A, const __bf16* __restrict__ W,
                   const float* __restrict__ bias, __bf16* __restrict__ C,
                   int N, int K, int relu)
{
    const int tid  = threadIdx.x;
    const int wave = tid >> 6, lane = tid & 63;
    const int quad = lane >> 4, ln = lane & 15;
    const int wm = wave >> 1, wn = wave & 1;
    const int rowbase = blockIdx.x * 128 + wm * 64;
    const int colbase = blockIdx.y * 128 + wn * 64;

    floatx4 acc[4][4];
    const floatx4 zf = {0.f, 0.f, 0.f, 0.f};
    #pragma unroll
    for (int m = 0; m < 4; m++)
        #pragma unroll
        for (int n = 0; n < 4; n++) acc[m][n] = zf;

    const int nk = K >> 5;
    for (int kt = 0; kt < nk; ++kt) {
        const int k = kt * 32 + quad * 8;
        bf16x8 af[4], bf[4];
        #pragma unroll
        for (int m = 0; m < 4; m++)
            af[m] = *(const bf16x8*)(A + (size_t)(rowbase + m * 16 + ln) * K + k);
        #pragma unroll
        for (int n = 0; n < 4; n++)
            bf[n] = *(const bf16x8*)(W + (size_t)(colbase + n * 16 + ln) * K + k);
        #pragma unroll
        for (int n = 0; n < 4; n++)
            #pragma unroll
            for (int m = 0; m < 4; m++)
                acc[m][n] = MFMA16(af[m], bf[n], acc[m][n]);
    }

    #pragma unroll
    for (int n = 0; n < 4; n++) {
        const int col = colbase + n * 16 + ln;
        const float bv = bias[col];
        #pragma unroll
        for (int m = 0; m < 4; m++)
            #pragma unroll
            for (int r = 0; r < 4; r++) {
                float val = acc[m][n][r] + bv;
                if (relu) val = fmaxf(val, 0.f);
                C[(size_t)(rowbase + m * 16 + quad * 4 + r) * N + col] = (__bf16)val;
            }
    }
}

// ---------------------------------------------------------------------------
// Head: out[b] = tanh(dot(x4[b][0..255], Wp) + bp).  4 lanes per row.
// ---------------------------------------------------------------------------
__global__ __launch_bounds__(256)
void head_kernel(const __bf16* __restrict__ x4, const float* __restrict__ Wp,
                 const float* __restrict__ bp, float* __restrict__ out)
{
    const int tid = threadIdx.x;
    const int wave = tid >> 6, lane = tid & 63;
    const int row = blockIdx.x * 64 + wave * 16 + (lane >> 2);
    const int part = lane & 3;
    const __bf16* xp = x4 + (size_t)row * 256 + part * 64;
    const float* wp = Wp + part * 64;
    float sum = 0.f;
    #pragma unroll
    for (int i = 0; i < 8; i++) {
        bf16x8 xv = *(const bf16x8*)(xp + i * 8);
        #pragma unroll
        for (int jj = 0; jj < 8; jj++) sum += (float)xv[jj] * wp[i * 8 + jj];
    }
    sum += __shfl_xor(sum, 1);
    sum += __shfl_xor(sum, 2);
    if (part == 0) out[row] = tanhf(sum + bp[0]);
}

// ---------------------------------------------------------------------------
extern "C" void kernel_launch(void* const* d_in, const int* in_sizes, int n_in,
                              void* d_out, int out_size, void* d_ws, size_t ws_size,
                              hipStream_t stream)
{
    const float* state = (const float*)d_in[0];
    const float* W_ih  = (const float*)d_in[1];
    const float* W_hh  = (const float*)d_in[2];
    const float* b_ih  = (const float*)d_in[3];
    const float* b_hh  = (const float*)d_in[4];
    const float* W1    = (const float*)d_in[5];
    const float* b1    = (const float*)d_in[6];
    const float* W2    = (const float*)d_in[7];
    const float* b2    = (const float*)d_in[8];
    const float* W3    = (const float*)d_in[9];
    const float* b3    = (const float*)d_in[10];
    const float* W4    = (const float*)d_in[11];
    const float* b4    = (const float*)d_in[12];
    const float* Wp    = (const float*)d_in[13];
    const float* bp    = (const float*)d_in[14];
    float* out = (float*)d_out;

    char* ws = (char*)d_ws;
    size_t off = 0;
    auto alloc = [&](size_t bytes) -> void* {
        void* p = ws + off;
        off += (bytes + 255) & ~(size_t)255;
        return p;
    };
    __bf16* Wg1   = (__bf16*)alloc(512 * 288 * 2);
    __bf16* W1p   = (__bf16*)alloc(1024 * 288 * 2);
    __bf16* W2b   = (__bf16*)alloc(1024 * 1024 * 2);
    __bf16* W3b   = (__bf16*)alloc(512 * 1024 * 2);
    __bf16* W4b   = (__bf16*)alloc(256 * 512 * 2);
    __bf16* Win_n = (__bf16*)alloc(256 * 32 * 2);
    __bf16* Whh_n = (__bf16*)alloc(256 * 256 * 2);
    float*  bsum  = (float*)alloc(512 * 4);
    float*  bihn  = (float*)alloc(256 * 4);
    float*  bhhn  = (float*)alloc(256 * 4);
    __bf16* x0    = (__bf16*)alloc((size_t)16384 * 288 * 2);
    __bf16* xA    = (__bf16*)alloc((size_t)16384 * 1024 * 2);  // x1, then x3
    __bf16* xB    = (__bf16*)alloc((size_t)16384 * 1024 * 2);  // x2, then x4

    prep_kernel<<<2048, 256, 0, stream>>>(W_ih, W_hh, b_ih, b_hh, W1, W2, W3, W4,
                                          Wg1, W1p, W2b, W3b, W4b, Win_n, Whh_n,
                                          bsum, bihn, bhhn);
    gru_kernel<<<256, 512, 0, stream>>>(state, Wg1, Win_n, Whh_n, bsum, bihn, bhhn, x0);
    gemm_bias_act<<<dim3(128, 8), 256, 0, stream>>>(x0, W1p, b1, xA, 1024, 288, 1);
    gemm_bias_act<<<dim3(128, 8), 256, 0, stream>>>(xA, W2b, b2, xB, 1024, 1024, 1);
    gemm_bias_act<<<dim3(128, 4), 256, 0, stream>>>(xB, W3b, b3, xA, 512, 1024, 1);
    gemm_bias_act<<<dim3(128, 2), 256, 0, stream>>>(xA, W4b, b4, xB, 256, 512, 1);
    head_kernel<<<256, 256, 0, stream>>>(xB, Wp, bp, out);
}

// Round 2
// 643.531 us; speedup vs baseline: 1.2127x; 1.2127x over previous
//
#include <hip/hip_runtime.h>

// ---------------------------------------------------------------------------
// Actor: GRU over V=20 vehicle slots (H=256) + MLP head 271->1024->1024->512->256->1
// B=16384, F=15. All GEMMs in bf16 MFMA (16x16x32), fp32 accumulate.
//
// GRU round-2 design: MFMA with A=weights (M=j gate cols), B=h (N=batch rows).
// D[j][row]: lane holds 4 consecutive j for one row -> 8B LDS writes, float4
// biases. 16 waves/block (1024 thr), wave owns a 16-col j-tile; 64 rows/block.
// Single 32KB hbuf + 2 barriers/step; 2x2KB double-buffered state slice.
// ---------------------------------------------------------------------------

typedef __attribute__((ext_vector_type(8))) __bf16 bf16x8;
typedef __attribute__((ext_vector_type(4))) __bf16 bf16x4;
typedef __attribute__((ext_vector_type(4))) float  floatx4;

#define MFMA16(a, b, c) __builtin_amdgcn_mfma_f32_16x16x32_bf16((a), (b), (c), 0, 0, 0)

__device__ __forceinline__ float sigmoid_f(float x) { return 1.f / (1.f + __expf(-x)); }
__device__ __forceinline__ float tanh_f(float x)    { return 1.f - 2.f / (1.f + __expf(2.f * x)); }

// ---------------------------------------------------------------------------
// Weight prep (unchanged from round 1):
//   Wg1  [512][288]  rows g in {r(0..255), z(256..511)}: [W_ih[g][0..14] | 0 x17 | W_hh[g][0..255]]
//   W1p  [1024][288] : [W1[o][0..14] | 0 x17 | W1[o][15..270]]
//   W2b  [1024][1024], W3b [512][1024], W4b [256][512]  : direct cvt
//   Win_n[256][32]   : [W_ih[512+j][0..14] | 0]
//   Whh_n[256][256]  : W_hh rows 512..767
//   bsum [512] = b_ih+b_hh (r,z);  bihn[256]=b_ih[512+]; bhhn[256]=b_hh[512+]
// ---------------------------------------------------------------------------
#define S0 147456u    // Wg1
#define S1 442368u    // + W1p (294912)
#define S2 1490944u   // + W2b (1048576)
#define S3 2015232u   // + W3b (524288)
#define S4 2146304u   // + W4b (131072)
#define S5 2154496u   // + Win_n (8192)
#define S6 2220032u   // + Whh_n (65536)
#define S7 2220544u   // + bsum (512)
#define S8 2221056u   // + bihn/bhhn (512)

__global__ void prep_kernel(const float* __restrict__ W_ih, const float* __restrict__ W_hh,
                            const float* __restrict__ b_ih, const float* __restrict__ b_hh,
                            const float* __restrict__ W1, const float* __restrict__ W2,
                            const float* __restrict__ W3, const float* __restrict__ W4,
                            __bf16* __restrict__ Wg1, __bf16* __restrict__ W1p,
                            __bf16* __restrict__ W2b, __bf16* __restrict__ W3b,
                            __bf16* __restrict__ W4b, __bf16* __restrict__ Win_n,
                            __bf16* __restrict__ Whh_n, float* __restrict__ bsum,
                            float* __restrict__ bihn, float* __restrict__ bhhn)
{
    for (unsigned i = blockIdx.x * blockDim.x + threadIdx.x; i < S8; i += gridDim.x * blockDim.x) {
        if (i < S0) {
            unsigned g = i / 288u, c = i % 288u;
            float v = (c < 15u) ? W_ih[g * 15u + c] : ((c < 32u) ? 0.f : W_hh[g * 256u + (c - 32u)]);
            Wg1[i] = (__bf16)v;
        } else if (i < S1) {
            unsigned t = i - S0, o = t / 288u, c = t % 288u;
            float v = (c < 15u) ? W1[o * 271u + c] : ((c < 32u) ? 0.f : W1[o * 271u + (c - 17u)]);
            W1p[t] = (__bf16)v;
        } else if (i < S2) {
            unsigned t = i - S1; W2b[t] = (__bf16)W2[t];
        } else if (i < S3) {
            unsigned t = i - S2; W3b[t] = (__bf16)W3[t];
        } else if (i < S4) {
            unsigned t = i - S3; W4b[t] = (__bf16)W4[t];
        } else if (i < S5) {
            unsigned t = i - S4, j = t / 32u, c = t % 32u;
            Win_n[t] = (__bf16)((c < 15u) ? W_ih[(512u + j) * 15u + c] : 0.f);
        } else if (i < S6) {
            unsigned t = i - S5; Whh_n[t] = (__bf16)W_hh[512u * 256u + t];
        } else if (i < S7) {
            unsigned t = i - S6; bsum[t] = b_ih[t] + b_hh[t];
        } else {
            unsigned t = i - S7;
            if (t < 256u) bihn[t] = b_ih[512u + t];
            else          bhhn[t - 256u] = b_hh[512u + t - 256u];
        }
    }
}

// ---------------------------------------------------------------------------
// GRU kernel. 256 blocks x 1024 threads (16 waves). 64 batch rows per block.
// Wave w owns gate columns j = w*16 .. w*16+15 (A-operand = weight rows).
// hbuf: [64 rows][256 j] bf16, XOR-swizzled at 16B chunks: chunk8' = chunk8 ^ (row&7).
// Per step: MFMAs (read hbuf) -> gate math -> barrier -> write hbuf -> barrier.
// ---------------------------------------------------------------------------
__global__ __launch_bounds__(1024)
void gru_kernel(const float* __restrict__ state,
                const __bf16* __restrict__ Wg1,  const __bf16* __restrict__ Win_n,
                const __bf16* __restrict__ Whh_n,
                const float* __restrict__ bsum, const float* __restrict__ bihn,
                const float* __restrict__ bhhn, __bf16* __restrict__ x0)
{
    __shared__ __bf16 hbuf[64 * 256];      // 32 KiB, swizzled
    __shared__ __bf16 sbuf[2][64 * 16];    // 2 x 2 KiB per-step state slices

    const int tid  = threadIdx.x;
    const int wave = tid >> 6;    // 0..15 : j-tile
    const int lane = tid & 63;
    const int q    = lane >> 4;   // k-quad
    const int ln   = lane & 15;
    const int b0   = blockIdx.x * 64;

    {   // zero h (h0 = 0)
        bf16x8 z = {};
        bf16x8* p = (bf16x8*)hbuf;
        for (int i = tid; i < 64 * 256 / 8; i += 1024) p[i] = z;
    }
    {   // stage state slice v=0 (1024 threads == 64 rows x 16 k)
        int row = tid >> 4, k = tid & 15;
        float s = (k < 15) ? state[(size_t)(b0 + row) * 300 + k] : 0.f;
        sbuf[0][row * 16 + k] = (__bf16)s;
    }

    // biases in D-layout: lane's 4 regs are j = wave*16 + q*4 + r
    const int jb = wave * 16 + q * 4;
    const floatx4 bsr = *(const floatx4*)(bsum + jb);
    const floatx4 bsz = *(const floatx4*)(bsum + 256 + jb);
    const floatx4 bin = *(const floatx4*)(bihn + jb);
    const floatx4 bhn = *(const floatx4*)(bhhn + jb);

    // weight row pointers (A-operand: lane ln = j row within tile)
    const __bf16* wr = Wg1 + (size_t)(wave * 16 + ln) * 288;
    const __bf16* wz = Wg1 + (size_t)(256 + wave * 16 + ln) * 288;
    const __bf16* wx = Win_n + (size_t)(wave * 16 + ln) * 32;
    const __bf16* wh = Whh_n + (size_t)(wave * 16 + ln) * 256;

    float hreg[4][4];   // [n-tile][r]  h_old in D-layout
    #pragma unroll
    for (int nt = 0; nt < 4; nt++)
        #pragma unroll
        for (int r = 0; r < 4; r++) hreg[nt][r] = 0.f;

    __syncthreads();

    #pragma unroll 1
    for (int v = 0; v < 20; ++v) {
        // stage next step's state slice into the other buffer (no conflict:
        // current step reads sbuf[v&1]; v-1's reads of this buffer completed
        // before the barrier that started this step)
        if (v < 19) {
            int row = tid >> 4, k = tid & 15;
            float s = (k < 15) ? state[(size_t)(b0 + row) * 300 + (v + 1) * 15 + k] : 0.f;
            sbuf[(v + 1) & 1][row * 16 + k] = (__bf16)s;
        }

        floatx4 ar[4], az[4], axn[4], ahn[4];
        const floatx4 zf = {0.f, 0.f, 0.f, 0.f};
        #pragma unroll
        for (int nt = 0; nt < 4; nt++) { ar[nt] = zf; az[nt] = zf; axn[nt] = zf; ahn[nt] = zf; }

        // ---- k-tile 0: state features (k=0..31; sbuf holds 16, rest zero) ----
        {
            bf16x8 a_r = *(const bf16x8*)(wr + q * 8);
            bf16x8 a_z = *(const bf16x8*)(wz + q * 8);
            bf16x8 a_x = *(const bf16x8*)(wx + q * 8);
            #pragma unroll
            for (int nt = 0; nt < 4; nt++) {
                bf16x8 b = {};
                if (q < 2) b = *(const bf16x8*)(&sbuf[v & 1][(nt * 16 + ln) * 16 + q * 8]);
                ar[nt]  = MFMA16(a_r, b, ar[nt]);
                az[nt]  = MFMA16(a_z, b, az[nt]);
                axn[nt] = MFMA16(a_x, b, axn[nt]);
            }
        }

        // ---- k-tiles over h (k = 32..287 of gate weights) ----
        #pragma unroll 2
        for (int kk = 0; kk < 8; ++kk) {
            bf16x8 a_r = *(const bf16x8*)(wr + 32 + kk * 32 + q * 8);
            bf16x8 a_z = *(const bf16x8*)(wz + 32 + kk * 32 + q * 8);
            bf16x8 a_h = *(const bf16x8*)(wh + kk * 32 + q * 8);
            #pragma unroll
            for (int nt = 0; nt < 4; nt++) {
                const int row = nt * 16 + ln;
                const bf16x8 b = *(const bf16x8*)(hbuf + row * 256 +
                                                  (((kk * 4 + q) ^ (row & 7)) << 3));
                ar[nt]  = MFMA16(a_r, b, ar[nt]);
                az[nt]  = MFMA16(a_z, b, az[nt]);
                ahn[nt] = MFMA16(a_h, b, ahn[nt]);
            }
        }

        // ---- gates (registers, D-layout: lane = (row=nt*16+ln, j=jb+r)) ----
        #pragma unroll
        for (int nt = 0; nt < 4; nt++)
            #pragma unroll
            for (int r = 0; r < 4; r++) {
                float rg = sigmoid_f(ar[nt][r] + bsr[r]);
                float zg = sigmoid_f(az[nt][r] + bsz[r]);
                float nn = tanh_f(axn[nt][r] + bin[r] + rg * (ahn[nt][r] + bhn[r]));
                hreg[nt][r] = (1.f - zg) * nn + zg * hreg[nt][r];
            }

        __syncthreads();   // all waves done reading hbuf

        // ---- write h_new: 4 consecutive j per lane -> 8B stores ----
        // chunk4(j) = wave*4 + q; swizzled c4' = c4 ^ ((row&7)<<1)  (keeps 16B
        // chunk pairing consistent with the read swizzle chunk8^(row&7))
        #pragma unroll
        for (int nt = 0; nt < 4; nt++) {
            const int row = nt * 16 + ln;
            bf16x4 hv;
            #pragma unroll
            for (int r = 0; r < 4; r++) hv[r] = (__bf16)hreg[nt][r];
            *(bf16x4*)(hbuf + row * 256 + ((((wave * 4 + q) ^ ((row & 7) << 1))) << 2)) = hv;
        }

        __syncthreads();
    }

    // ---- epilogue: x0 = [state[:,0,:] (15) | 0-pad to 32 | h (256)] ----
    #pragma unroll
    for (int nt = 0; nt < 4; nt++) {
        const int row = nt * 16 + ln;
        bf16x4 hv;
        #pragma unroll
        for (int r = 0; r < 4; r++) hv[r] = (__bf16)hreg[nt][r];
        *(bf16x4*)(x0 + (size_t)(b0 + row) * 288 + 32 + jb) = hv;
    }
    for (int i = tid; i < 64 * 32; i += 1024) {
        int row = i >> 5, c = i & 31;
        float s = (c < 15) ? state[(size_t)(b0 + row) * 300 + c] : 0.f;
        x0[(size_t)(b0 + row) * 288 + c] = (__bf16)s;
    }
}

// ---------------------------------------------------------------------------
// Generic MFMA GEMM:  C[M][N] = act(A[M][K] @ W[N][K]^T + bias), bf16 in/out.
// Block = 256 thr (4 waves, 2x2), block tile 128x128, wave tile 64x64.
// ---------------------------------------------------------------------------
__global__ __launch_bounds__(256)
void gemm_bias_act(const __bf16* __restrict__ A, const __bf16* __restrict__ W,
                   const float* __restrict__ bias, __bf16* __restrict__ C,
                   int N, int K, int relu)
{
    const int tid  = threadIdx.x;
    const int wave = tid >> 6, lane = tid & 63;
    const int quad = lane >> 4, ln = lane & 15;
    const int wm = wave >> 1, wn = wave & 1;
    const int rowbase = blockIdx.x * 128 + wm * 64;
    const int colbase = blockIdx.y * 128 + wn * 64;

    floatx4 acc[4][4];
    const floatx4 zf = {0.f, 0.f, 0.f, 0.f};
    #pragma unroll
    for (int m = 0; m < 4; m++)
        #pragma unroll
        for (int n = 0; n < 4; n++) acc[m][n] = zf;

    const int nk = K >> 5;
    for (int kt = 0; kt < nk; ++kt) {
        const int k = kt * 32 + quad * 8;
        bf16x8 af[4], bf[4];
        #pragma unroll
        for (int m = 0; m < 4; m++)
            af[m] = *(const bf16x8*)(A + (size_t)(rowbase + m * 16 + ln) * K + k);
        #pragma unroll
        for (int n = 0; n < 4; n++)
            bf[n] = *(const bf16x8*)(W + (size_t)(colbase + n * 16 + ln) * K + k);
        #pragma unroll
        for (int n = 0; n < 4; n++)
            #pragma unroll
            for (int m = 0; m < 4; m++)
                acc[m][n] = MFMA16(af[m], bf[n], acc[m][n]);
    }

    #pragma unroll
    for (int n = 0; n < 4; n++) {
        const int col = colbase + n * 16 + ln;
        const float bv = bias[col];
        #pragma unroll
        for (int m = 0; m < 4; m++)
            #pragma unroll
            for (int r = 0; r < 4; r++) {
                float val = acc[m][n][r] + bv;
                if (relu) val = fmaxf(val, 0.f);
                C[(size_t)(rowbase + m * 16 + quad * 4 + r) * N + col] = (__bf16)val;
            }
    }
}

// ---------------------------------------------------------------------------
// Head: out[b] = tanh(dot(x4[b][0..255], Wp) + bp).  4 lanes per row.
// ---------------------------------------------------------------------------
__global__ __launch_bounds__(256)
void head_kernel(const __bf16* __restrict__ x4, const float* __restrict__ Wp,
                 const float* __restrict__ bp, float* __restrict__ out)
{
    const int tid = threadIdx.x;
    const int wave = tid >> 6, lane = tid & 63;
    const int row = blockIdx.x * 64 + wave * 16 + (lane >> 2);
    const int part = lane & 3;
    const __bf16* xp = x4 + (size_t)row * 256 + part * 64;
    const float* wp = Wp + part * 64;
    float sum = 0.f;
    #pragma unroll
    for (int i = 0; i < 8; i++) {
        bf16x8 xv = *(const bf16x8*)(xp + i * 8);
        #pragma unroll
        for (int jj = 0; jj < 8; jj++) sum += (float)xv[jj] * wp[i * 8 + jj];
    }
    sum += __shfl_xor(sum, 1);
    sum += __shfl_xor(sum, 2);
    if (part == 0) out[row] = tanhf(sum + bp[0]);
}

// ---------------------------------------------------------------------------
extern "C" void kernel_launch(void* const* d_in, const int* in_sizes, int n_in,
                              void* d_out, int out_size, void* d_ws, size_t ws_size,
                              hipStream_t stream)
{
    const float* state = (const float*)d_in[0];
    const float* W_ih  = (const float*)d_in[1];
    const float* W_hh  = (const float*)d_in[2];
    const float* b_ih  = (const float*)d_in[3];
    const float* b_hh  = (const float*)d_in[4];
    const float* W1    = (const float*)d_in[5];
    const float* b1    = (const float*)d_in[6];
    const float* W2    = (const float*)d_in[7];
    const float* b2    = (const float*)d_in[8];
    const float* W3    = (const float*)d_in[9];
    const float* b3    = (const float*)d_in[10];
    const float* W4    = (const float*)d_in[11];
    const float* b4    = (const float*)d_in[12];
    const float* Wp    = (const float*)d_in[13];
    const float* bp    = (const float*)d_in[14];
    float* out = (float*)d_out;

    char* ws = (char*)d_ws;
    size_t off = 0;
    auto alloc = [&](size_t bytes) -> void* {
        void* p = ws + off;
        off += (bytes + 255) & ~(size_t)255;
        return p;
    };
    __bf16* Wg1   = (__bf16*)alloc(512 * 288 * 2);
    __bf16* W1p   = (__bf16*)alloc(1024 * 288 * 2);
    __bf16* W2b   = (__bf16*)alloc(1024 * 1024 * 2);
    __bf16* W3b   = (__bf16*)alloc(512 * 1024 * 2);
    __bf16* W4b   = (__bf16*)alloc(256 * 512 * 2);
    __bf16* Win_n = (__bf16*)alloc(256 * 32 * 2);
    __bf16* Whh_n = (__bf16*)alloc(256 * 256 * 2);
    float*  bsum  = (float*)alloc(512 * 4);
    float*  bihn  = (float*)alloc(256 * 4);
    float*  bhhn  = (float*)alloc(256 * 4);
    __bf16* x0    = (__bf16*)alloc((size_t)16384 * 288 * 2);
    __bf16* xA    = (__bf16*)alloc((size_t)16384 * 1024 * 2);  // x1, then x3
    __bf16* xB    = (__bf16*)alloc((size_t)16384 * 1024 * 2);  // x2, then x4

    prep_kernel<<<2048, 256, 0, stream>>>(W_ih, W_hh, b_ih, b_hh, W1, W2, W3, W4,
                                          Wg1, W1p, W2b, W3b, W4b, Win_n, Whh_n,
                                          bsum, bihn, bhhn);
    gru_kernel<<<256, 1024, 0, stream>>>(state, Wg1, Win_n, Whh_n, bsum, bihn, bhhn, x0);
    gemm_bias_act<<<dim3(128, 8), 256, 0, stream>>>(x0, W1p, b1, xA, 1024, 288, 1);
    gemm_bias_act<<<dim3(128, 8), 256, 0, stream>>>(xA, W2b, b2, xB, 1024, 1024, 1);
    gemm_bias_act<<<dim3(128, 4), 256, 0, stream>>>(xB, W3b, b3, xA, 512, 1024, 1);
    gemm_bias_act<<<dim3(128, 2), 256, 0, stream>>>(xA, W4b, b4, xB, 256, 512, 1);
    head_kernel<<<256, 256, 0, stream>>>(xB, Wp, bp, out);
}